// Round 6
// baseline (4578.838 us; speedup 1.0000x reference)
//
#include <hip/hip_runtime.h>
#include <stdint.h>

// Persistent-kernel LSTM, MI355X — R6: R5 skeleton + distributed no-RMW flag barrier.
//   - 256 WGs: 4 independent batch-groups (16 samples) × 64 WGs (16 hidden each, all 4 gates)
//   - W_hh slice resident in VGPRs as bf16 MFMA B-fragments (128 regs/lane)
//   - h exchange: double-buffered bf16, sc0 sc1 (memory-side coherence point)
//   - R6 sync: per-WG 64B flag line, per-WAVE sub-flag dword stored right after that
//     wave's own h-store drain (no atomic RMW, no pre-flag barrier). Consumer wave 0
//     polls ALL 64 lines with one global_load_dwordx4 (lane l -> line l), checks 4 dwords.
//     R5's single-line atomicAdd serialized ~64 RMWs/step (~6k cy) -> all parallel now.
//   - LDS partial stride 17 -> 20: write banks (80*lq+20r+lr)%32 -> exact 2-way (free).
// ws layout: [0,16KB) flags (4 grp x 64 lines x 64B) | [16K, +256KB) h dbuf
//            | [0x44000, +4MB) embW fp32.  Total 4.47 MB.

#define T_STEPS 1024
#define BATCH   64
#define EDIM    256
#define HDIM    1024

typedef float    f32x4  __attribute__((ext_vector_type(4)));
typedef short    bf16x8 __attribute__((ext_vector_type(8)));
typedef uint32_t u32x4  __attribute__((ext_vector_type(4)));

__device__ __forceinline__ unsigned short f2bf(float f) {
  union { float f; uint32_t u; } v; v.f = f;
  uint32_t r = (v.u + 0x7FFFu + ((v.u >> 16) & 1u)) >> 16;  // RNE
  return (unsigned short)r;
}
__device__ __forceinline__ float sigf(float x) { return 1.f / (1.f + __expf(-x)); }
__device__ __forceinline__ float tanh_fast(float x) {
  float ax = fabsf(x);
  float e  = __expf(-2.f * ax);
  float t  = (1.f - e) / (1.f + e);
  return copysignf(t, x);
}

__global__ void __launch_bounds__(256)
embw_kernel(const float* __restrict__ emb, const float* __restrict__ W_ih,
            const float* __restrict__ b_ih, const float* __restrict__ b_hh,
            float* __restrict__ embW)
{
  __shared__ float ev[EDIM];
  const int v   = blockIdx.y;
  const int col = blockIdx.x * 256 + threadIdx.x;
  ev[threadIdx.x] = emb[v * EDIM + threadIdx.x];
  __syncthreads();
  const float4* wr = (const float4*)(W_ih + (size_t)col * EDIM);
  float acc = b_ih[col] + b_hh[col];
#pragma unroll 4
  for (int e4 = 0; e4 < EDIM / 4; ++e4) {
    const float4 q = wr[e4];
    acc += ev[4*e4+0] * q.x + ev[4*e4+1] * q.y + ev[4*e4+2] * q.z + ev[4*e4+3] * q.w;
  }
  embW[(size_t)v * (4 * HDIM) + col] = acc;
}

__global__ void __launch_bounds__(256, 1)
lstm_kernel(const int* __restrict__ tokens, const int* __restrict__ seq_len,
            const float* __restrict__ W_hh, const float* __restrict__ embW,
            uint32_t* hbuf, uint32_t* flags, float* __restrict__ out)
{
  const int tid = threadIdx.x;
  const int bid = blockIdx.x;     // 0..255
  const int g   = bid & 3;        // batch group
  const int wig = bid >> 2;       // WG within group: hidden slice
  const int hb  = wig << 4;       // hidden base (16 per WG)
  const int gs0 = g << 4;         // sample base (16 per group)
  const int w   = tid >> 6;       // wave 0..3 (K-split: 256 each)
  const int l   = tid & 63;
  const int lr  = l & 15;         // MFMA m / n index
  const int lq  = l >> 4;         // MFMA k-quad

  // ---- stage W_hh slice into registers as bf16 MFMA B-fragments ----
  bf16x8 bfrag[4][8];             // [gate][kstep]
#pragma unroll
  for (int n = 0; n < 4; ++n) {
    const float* wrow = W_hh + (size_t)(n * HDIM + hb + lr) * HDIM + w * 256 + lq * 8;
#pragma unroll
    for (int ks = 0; ks < 8; ++ks) {
      union { bf16x8 v; unsigned short u[8]; } bu;
#pragma unroll
      for (int e = 0; e < 8; ++e) bu.u[e] = f2bf(wrow[ks * 32 + e]);
      bfrag[n][ks] = bu.v;
    }
  }

  const int s  = tid >> 4;        // pointwise: sample-local
  const int j  = tid & 15;        // pointwise: hidden-local
  const int b  = gs0 + s;
  const int sl = seq_len[b];
  float c = 0.f, lastc = 0.f;

  // stride 20: write banks (80lq+20r+lr)%32 -> lq pairs {0,2},{1,3} alias = 2-way (free)
  __shared__ float part[4][4][16][20];   // [wave][gate][m][n]

  uint32_t* flags_g = flags + g * 1024;  // 64 lines x 16 dwords (64B) per group

  const uint32_t voff_base = (uint32_t)((gs0 + lr) * (HDIM * 2) + (w * 512 + lq * 16));

  for (int t = 0; t < T_STEPS; ++t) {
    // embW gather — its latency folds into the A-load drain below
    const int tok = tokens[t * BATCH + b];
    const float* er = embW + (size_t)tok * (4 * HDIM) + hb + j;
    float gi = er[0], gf = er[HDIM], gg = er[2 * HDIM], go = er[3 * HDIM];

    if (t > 0) {
      const uint32_t voff = ((uint32_t)((t - 1) & 1)) * (BATCH * HDIM * 2) + voff_base;
      u32x4 r0, r1, r2, r3, r4, r5, r6, r7;
      // 8 pipelined cache-bypassing 16B loads + single drain (proven R2 path)
      asm volatile(
        "global_load_dwordx4 %0, %8, %9 sc0 sc1\n\t"
        "global_load_dwordx4 %1, %8, %9 offset:64 sc0 sc1\n\t"
        "global_load_dwordx4 %2, %8, %9 offset:128 sc0 sc1\n\t"
        "global_load_dwordx4 %3, %8, %9 offset:192 sc0 sc1\n\t"
        "global_load_dwordx4 %4, %8, %9 offset:256 sc0 sc1\n\t"
        "global_load_dwordx4 %5, %8, %9 offset:320 sc0 sc1\n\t"
        "global_load_dwordx4 %6, %8, %9 offset:384 sc0 sc1\n\t"
        "global_load_dwordx4 %7, %8, %9 offset:448 sc0 sc1\n\t"
        "s_waitcnt vmcnt(0)"
        : "=&v"(r0), "=&v"(r1), "=&v"(r2), "=&v"(r3),
          "=&v"(r4), "=&v"(r5), "=&v"(r6), "=&v"(r7)
        : "v"(voff), "s"(hbuf)
        : "memory");

      u32x4 areg[8] = {r0, r1, r2, r3, r4, r5, r6, r7};
      f32x4 a0 = {0.f,0.f,0.f,0.f}, a1 = a0, a2 = a0, a3 = a0;
#pragma unroll
      for (int ks = 0; ks < 8; ++ks) {
        union { bf16x8 v; u32x4 u; } au;
        au.u = areg[ks];
        a0 = __builtin_amdgcn_mfma_f32_16x16x32_bf16(au.v, bfrag[0][ks], a0, 0, 0, 0);
        a1 = __builtin_amdgcn_mfma_f32_16x16x32_bf16(au.v, bfrag[1][ks], a1, 0, 0, 0);
        a2 = __builtin_amdgcn_mfma_f32_16x16x32_bf16(au.v, bfrag[2][ks], a2, 0, 0, 0);
        a3 = __builtin_amdgcn_mfma_f32_16x16x32_bf16(au.v, bfrag[3][ks], a3, 0, 0, 0);
      }
#pragma unroll
      for (int r = 0; r < 4; ++r) {        // C layout: col=lane&15, row=(lane>>4)*4+reg
        const int m = lq * 4 + r;
        part[w][0][m][lr] = a0[r];
        part[w][1][m][lr] = a1[r];
        part[w][2][m][lr] = a2[r];
        part[w][3][m][lr] = a3[r];
      }
    }
    __syncthreads();

    if (t > 0) {
#pragma unroll
      for (int ww = 0; ww < 4; ++ww) {
        gi += part[ww][0][s][j];
        gf += part[ww][1][s][j];
        gg += part[ww][2][s][j];
        go += part[ww][3][s][j];
      }
    }

    const float cn = sigf(gf) * c + sigf(gi) * tanh_fast(gg);
    const float hn = sigf(go) * tanh_fast(cn);
    c = cn;
    if ((t == 0) || (t < sl)) lastc = cn;   // freeze mask (step 0 always valid)

    if (t + 1 < T_STEPS) {
      // h -> bf16 pair -> store to coherence point
      const unsigned short hu = f2bf(hn);
      const int other = __shfl_xor((int)hu, 1);
      if ((j & 1) == 0) {
        const uint32_t pk = (uint32_t)hu | ((uint32_t)(unsigned short)other << 16);
        __hip_atomic_store(hbuf + (t & 1) * (BATCH * HDIM / 2) + b * (HDIM / 2) + ((hb + j) >> 1),
                           pk, __ATOMIC_RELAXED, __HIP_MEMORY_SCOPE_AGENT);
      }
      // per-WAVE drain + sub-flag store: wave w attests samples 4w..4w+3 (its h rows).
      // No RMW, 64B-separated lines -> all 256 flag stores per group-step are parallel.
      asm volatile("s_waitcnt vmcnt(0)" ::: "memory");
      if (l == 0) {
        const uint32_t foff = (uint32_t)((wig << 6) + (w << 2));   // line wig, dword w
        asm volatile("global_store_dword %0, %1, %2 sc0 sc1"
                     :: "v"(foff), "v"((uint32_t)(t + 1)), "s"(flags_g) : "memory");
      }
      if (w == 0) {
        // wave 0: lane l polls WG l's flag line (one dwordx4 = 64 parallel line reads)
        const uint32_t target = (uint32_t)t;   // pass when all sub-flags > t
        u32x4 fv;
        do {
          asm volatile("global_load_dwordx4 %0, %1, %2 sc0 sc1\n\ts_waitcnt vmcnt(0)"
                       : "=v"(fv) : "v"((uint32_t)(l << 6)), "s"(flags_g) : "memory");
        } while (!__all((int)(fv.x > target && fv.y > target &&
                              fv.z > target && fv.w > target)));
      }
      __syncthreads();   // release waves into t+1 (also WAR-protects `part`)
    }
  }

  out[(size_t)b * HDIM + hb + j] = lastc;
}

extern "C" void kernel_launch(void* const* d_in, const int* in_sizes, int n_in,
                              void* d_out, int out_size, void* d_ws, size_t ws_size,
                              hipStream_t stream) {
  const int*   tokens = (const int*)d_in[0];
  const int*   seqlen = (const int*)d_in[1];
  const float* emb    = (const float*)d_in[2];
  const float* W_ih   = (const float*)d_in[3];
  const float* W_hh   = (const float*)d_in[4];
  const float* b_ih   = (const float*)d_in[5];
  const float* b_hh   = (const float*)d_in[6];
  float* out = (float*)d_out;

  uint8_t*  ws    = (uint8_t*)d_ws;
  uint32_t* flags = (uint32_t*)ws;                  // 4 grp x 64 lines x 64B = 16 KB
  uint32_t* hbuf  = (uint32_t*)(ws + 16384);        // 2 x 64*1024 bf16 = 256 KB
  float*    embW  = (float*)(ws + 0x44000);         // 256*4096 fp32 = 4 MB (tot 4.47 MB)

  hipMemsetAsync(ws, 0, 16384, stream);             // zero flag lines every launch
  embw_kernel<<<dim3(16, 256), 256, 0, stream>>>(emb, W_ih, b_ih, b_hh, embW);
  lstm_kernel<<<dim3(256), 256, 0, stream>>>(tokens, seqlen, W_hh, embW, hbuf, flags, out);
}

// Round 7
// 4560.674 us; speedup vs baseline: 1.0040x; 1.0040x over previous
//
#include <hip/hip_runtime.h>
#include <hip/hip_fp16.h>
#include <stdint.h>

// Persistent-kernel LSTM, MI355X — R7: poll-on-data (epoch-tagged h), no flags, no drains.
//   - 8 groups x 32 WGs; group g owns samples 8g..8g+7; WG owns 32 hidden x 4 gates.
//   - W_hh slice in VGPRs as bf16 B-fragments (bfrag 256 VGPR/lane); K split across 4 waves.
//   - h granule = 8B {2xbf16, epoch=t+1}; stores fire-and-forget sc0 sc1; consumers poll
//     their A-fragment loads until all embedded epochs == t. Sync = ONE memory leg.
//   - WAR-safe: WG stores h(t+2) only after validating all h(t+1), which requires every WG
//     to have finished (vmcnt-drained) its h(t) reads. Double buffer suffices.
//   - M=8 rides 16x16x32 MFMA via row aliasing (rows 8..15 same addr -> broadcast).
//   - embW precomputed as fp16 (2 MB): ws total 2.5 MB (proven-safe range).
// ws: [0, 512KB) hbuf: 8 grp x {2 buf x 8 rows x 4KB} | [0x80000, +2MB) embW fp16.
//     No memset needed: poison/zero never matches epoch targets 1..1023.

#define T_STEPS 1024
#define BATCH   64
#define EDIM    256
#define HDIM    1024

typedef float    f32x4  __attribute__((ext_vector_type(4)));
typedef short    bf16x8 __attribute__((ext_vector_type(8)));
typedef uint32_t u32x4  __attribute__((ext_vector_type(4)));
typedef uint32_t u32x2  __attribute__((ext_vector_type(2)));

__device__ __forceinline__ unsigned short f2bf(float f) {
  union { float f; uint32_t u; } v; v.f = f;
  uint32_t r = (v.u + 0x7FFFu + ((v.u >> 16) & 1u)) >> 16;  // RNE
  return (unsigned short)r;
}
__device__ __forceinline__ float sigf(float x) { return 1.f / (1.f + __expf(-x)); }
__device__ __forceinline__ float tanh_fast(float x) {
  float ax = fabsf(x);
  float e  = __expf(-2.f * ax);
  float t  = (1.f - e) / (1.f + e);
  return copysignf(t, x);
}

__global__ void __launch_bounds__(256)
embw_kernel(const float* __restrict__ emb, const float* __restrict__ W_ih,
            const float* __restrict__ b_ih, const float* __restrict__ b_hh,
            __half* __restrict__ embW)
{
  __shared__ float ev[EDIM];
  const int v   = blockIdx.y;
  const int col = blockIdx.x * 256 + threadIdx.x;
  ev[threadIdx.x] = emb[v * EDIM + threadIdx.x];
  __syncthreads();
  const float4* wr = (const float4*)(W_ih + (size_t)col * EDIM);
  float acc = b_ih[col] + b_hh[col];
#pragma unroll 4
  for (int e4 = 0; e4 < EDIM / 4; ++e4) {
    const float4 q = wr[e4];
    acc += ev[4*e4+0] * q.x + ev[4*e4+1] * q.y + ev[4*e4+2] * q.z + ev[4*e4+3] * q.w;
  }
  embW[(size_t)v * (4 * HDIM) + col] = __float2half(acc);
}

__global__ void __launch_bounds__(256, 1)
lstm_kernel(const int* __restrict__ tokens, const int* __restrict__ seq_len,
            const float* __restrict__ W_hh, const __half* __restrict__ embW,
            uint8_t* hbuf, float* __restrict__ out)
{
  const int tid  = threadIdx.x;
  const int bid  = blockIdx.x;     // 0..255
  const int g    = bid & 7;        // group (8 samples each)
  const int slot = bid >> 3;       // 0..31: hidden slice
  const int hb   = slot << 5;      // 32 hidden per WG
  const int w    = tid >> 6;       // wave 0..3 (K-split: 256 each)
  const int l    = tid & 63;
  const int lr   = l & 15;
  const int lq   = l >> 4;

  uint8_t* hbuf_g = hbuf + (size_t)g * 65536;   // 2 buf x 8 rows x 4KB

  // ---- stage W_hh slice: bfrag[gate][ntile][ks]; B[k][n]=W_hh[gate-row n][k] ----
  bf16x8 bfrag[4][2][8];          // 256 VGPRs
#pragma unroll
  for (int n = 0; n < 4; ++n)
#pragma unroll
    for (int jt = 0; jt < 2; ++jt) {
      const int col = hb + jt * 16 + lr;
#pragma unroll
      for (int ks = 0; ks < 8; ++ks) {
        const float* wrow = W_hh + (size_t)(n * HDIM + col) * HDIM + w * 256 + ks * 32 + lq * 8;
        union { bf16x8 v; unsigned short u[8]; } bu;
#pragma unroll
        for (int e = 0; e < 8; ++e) bu.u[e] = f2bf(wrow[e]);
        bfrag[n][jt][ks] = bu.v;
      }
    }

  // pointwise: 256 threads = 8 samples x 32 hidden
  const int s  = tid >> 5;        // 0..7
  const int j  = tid & 31;        // 0..31
  const int jt = j >> 4, jn = j & 15;
  const int b  = g * 8 + s;
  const int sl = seq_len[b];
  float c = 0.f, lastc = 0.f;

  __shared__ float part[4][8][8][17];   // [wave][tile=gate*2+jt][m(sample)][n]

  // A granule addressing: row (lr&7)*4096, k-byte = k*4 (8B per 2 h)
  const uint32_t voff_base = (uint32_t)((lr & 7) * 4096 + w * 1024 + lq * 32);

  for (int t = 0; t < T_STEPS; ++t) {
    // embW gather (fp16, plain cached loads) — overlaps the poll below
    const int tok = tokens[t * BATCH + b];
    const __half* er = embW + (size_t)tok * (4 * HDIM) + hb + j;
    float gi = __half2float(er[0]),        gf = __half2float(er[HDIM]),
          gg = __half2float(er[2 * HDIM]), go = __half2float(er[3 * HDIM]);

    if (t > 0) {
      const uint32_t voff = ((uint32_t)((t - 1) & 1)) * 32768u + voff_base;
      const uint32_t target = (uint32_t)t;      // h(t-1) tagged with epoch t
      u32x4 A[16];
      // poll: issue all 16 tagged-fragment loads, validate embedded epochs, retry if stale
      for (;;) {
        asm volatile(
          "global_load_dwordx4 %0, %16, %17 sc0 sc1\n\t"
          "global_load_dwordx4 %1, %16, %17 offset:16 sc0 sc1\n\t"
          "global_load_dwordx4 %2, %16, %17 offset:128 sc0 sc1\n\t"
          "global_load_dwordx4 %3, %16, %17 offset:144 sc0 sc1\n\t"
          "global_load_dwordx4 %4, %16, %17 offset:256 sc0 sc1\n\t"
          "global_load_dwordx4 %5, %16, %17 offset:272 sc0 sc1\n\t"
          "global_load_dwordx4 %6, %16, %17 offset:384 sc0 sc1\n\t"
          "global_load_dwordx4 %7, %16, %17 offset:400 sc0 sc1\n\t"
          "global_load_dwordx4 %8, %16, %17 offset:512 sc0 sc1\n\t"
          "global_load_dwordx4 %9, %16, %17 offset:528 sc0 sc1\n\t"
          "global_load_dwordx4 %10, %16, %17 offset:640 sc0 sc1\n\t"
          "global_load_dwordx4 %11, %16, %17 offset:656 sc0 sc1\n\t"
          "global_load_dwordx4 %12, %16, %17 offset:768 sc0 sc1\n\t"
          "global_load_dwordx4 %13, %16, %17 offset:784 sc0 sc1\n\t"
          "global_load_dwordx4 %14, %16, %17 offset:896 sc0 sc1\n\t"
          "global_load_dwordx4 %15, %16, %17 offset:912 sc0 sc1\n\t"
          "s_waitcnt vmcnt(0)"
          : "=&v"(A[0]), "=&v"(A[1]), "=&v"(A[2]), "=&v"(A[3]),
            "=&v"(A[4]), "=&v"(A[5]), "=&v"(A[6]), "=&v"(A[7]),
            "=&v"(A[8]), "=&v"(A[9]), "=&v"(A[10]), "=&v"(A[11]),
            "=&v"(A[12]), "=&v"(A[13]), "=&v"(A[14]), "=&v"(A[15])
          : "v"(voff), "s"(hbuf_g)
          : "memory");
        bool ok = true;
#pragma unroll
        for (int i = 0; i < 16; ++i)
          ok &= (A[i].y == target) & (A[i].w == target);
        if (ok) break;
        __builtin_amdgcn_s_sleep(1);
      }

      f32x4 acc[4][2];
#pragma unroll
      for (int n = 0; n < 4; ++n) {
        acc[n][0] = (f32x4){0.f, 0.f, 0.f, 0.f};
        acc[n][1] = (f32x4){0.f, 0.f, 0.f, 0.f};
      }
#pragma unroll
      for (int ks = 0; ks < 8; ++ks) {
        union { bf16x8 v; uint32_t u[4]; } au;
        au.u[0] = A[2*ks].x;  au.u[1] = A[2*ks].z;
        au.u[2] = A[2*ks+1].x; au.u[3] = A[2*ks+1].z;
#pragma unroll
        for (int n = 0; n < 4; ++n) {
          acc[n][0] = __builtin_amdgcn_mfma_f32_16x16x32_bf16(au.v, bfrag[n][0][ks], acc[n][0], 0, 0, 0);
          acc[n][1] = __builtin_amdgcn_mfma_f32_16x16x32_bf16(au.v, bfrag[n][1][ks], acc[n][1], 0, 0, 0);
        }
      }
      // C layout: col=lane&15, row=lq*4+r; rows 8..15 are alias duplicates -> drop
      if (lq < 2) {
#pragma unroll
        for (int r = 0; r < 4; ++r) {
          const int m = lq * 4 + r;
#pragma unroll
          for (int n = 0; n < 4; ++n) {
            part[w][n * 2 + 0][m][lr] = acc[n][0][r];
            part[w][n * 2 + 1][m][lr] = acc[n][1][r];
          }
        }
      }
    }
    __syncthreads();   // B1: partials visible to pointwise

    if (t > 0) {
#pragma unroll
      for (int ww = 0; ww < 4; ++ww) {
        gi += part[ww][0 + jt][s][jn];
        gf += part[ww][2 + jt][s][jn];
        gg += part[ww][4 + jt][s][jn];
        go += part[ww][6 + jt][s][jn];
      }
    }

    const float cn = sigf(gf) * c + sigf(gi) * tanh_fast(gg);
    const float hn = sigf(go) * tanh_fast(cn);
    c = cn;
    if ((t == 0) || (t < sl)) lastc = cn;   // freeze mask (step 0 always valid)

    __syncthreads();   // B2: part WAR (reads done before next MFMA's writes)

    if (t + 1 < T_STEPS) {
      // h granule {2xbf16, epoch=t+1} -> fire-and-forget store (no drain, no flag)
      const unsigned short hu = f2bf(hn);
      const int other = __shfl_xor((int)hu, 1);
      if ((j & 1) == 0) {
        u32x2 gr;
        gr.x = (uint32_t)hu | ((uint32_t)(unsigned short)other << 16);
        gr.y = (uint32_t)(t + 1);
        const uint32_t soff = (uint32_t)((t & 1) * 32768 + s * 4096 + (hb + j) * 4);
        asm volatile("global_store_dwordx2 %0, %1, %2 sc0 sc1"
                     :: "v"(soff), "v"(gr), "s"(hbuf_g) : "memory");
      }
    }
  }

  out[(size_t)b * HDIM + hb + j] = lastc;
}

extern "C" void kernel_launch(void* const* d_in, const int* in_sizes, int n_in,
                              void* d_out, int out_size, void* d_ws, size_t ws_size,
                              hipStream_t stream) {
  const int*   tokens = (const int*)d_in[0];
  const int*   seqlen = (const int*)d_in[1];
  const float* emb    = (const float*)d_in[2];
  const float* W_ih   = (const float*)d_in[3];
  const float* W_hh   = (const float*)d_in[4];
  const float* b_ih   = (const float*)d_in[5];
  const float* b_hh   = (const float*)d_in[6];
  float* out = (float*)d_out;

  uint8_t* ws   = (uint8_t*)d_ws;
  uint8_t* hbuf = ws;                         // 512 KB (epoch-validated, no memset needed)
  __half*  embW = (__half*)(ws + 0x80000);    // 2 MB; total 2.5 MB

  embw_kernel<<<dim3(16, 256), 256, 0, stream>>>(emb, W_ih, b_ih, b_hh, embW);
  lstm_kernel<<<dim3(256), 256, 0, stream>>>(tokens, seqlen, W_hh, embW, hbuf, out);
}